// Round 13
// baseline (98.508 us; speedup 1.0000x reference)
//
#include <hip/hip_runtime.h>
#include <math.h>

#define Dd 96
#define Nn 48

// Fast full-precision f64 reciprocal: v_rcp_f64 + 2 Newton steps (<=1 ulp).
__device__ __forceinline__ double frcp(double x) {
    double r = __builtin_amdgcn_rcp(x);
    r = fma(fma(-x, r, 1.0), r, r);
    r = fma(fma(-x, r, 1.0), r, r);
    return r;
}

// Wave-uniform f64 broadcast from a lane (v_readlane -> SGPR pair, no LDS).
__device__ __forceinline__ double rdlane(double v, int srcLane) {
    union { double d; int i[2]; } u; u.d = v;
    int lo = __builtin_amdgcn_readlane(u.i[0], srcLane);
    int hi = __builtin_amdgcn_readlane(u.i[1], srcLane);
    union { int i[2]; double d; } w; w.i[0] = lo; w.i[1] = hi;
    return w.d;
}

// ============================================================================
// R32: single fused kernel. R31's rank-6 async pipeline + the G-build fused
// back in REGISTER form: each wave computes its own 6 rows of
// A = I*(1-flag) - P P^T straight into rr from P (18KB, L1-resident),
// element-wise t-ascending accumulation (bit-identical to build_g). Deletes
// the build_g dispatch (+launch gap) and the Mg global round-trip; wave 0's
// prefactor(0) starts as soon as its OWN rows are built (no barrier).
// Waves with wave > s_end (rows >= n, never read) skip the pipeline.
// ============================================================================
__global__ __launch_bounds__(1024, 1) void slater_fused(const float* __restrict__ P,
                                                        const int* __restrict__ occ,
                                                        float* __restrict__ out,
                                                        unsigned* __restrict__ cnt) {
    __shared__ double Sbuf[16][6][Dd];  // 73,728 B: one S buffer per step
    __shared__ double ev16[16][6];      // per-panel emissions
    __shared__ int    evmask16[16], sdead16[16];
    __shared__ double evm[6];           // tail emissions
    __shared__ int    evmmask;
    __shared__ double gs_runprod;       // guard-state chain (owner-serialized)
    __shared__ int    gs_dead;
    __shared__ int    step_pub;         // highest published step (monotonic)
    __shared__ unsigned char flag[Dd];

    const int tid  = threadIdx.x;
    const int k    = blockIdx.x;
    const int n    = Dd - Nn + k + 1;   // xmax
    const int lane = tid & 63;
    const int wave = tid >> 6;          // 0..15
    const int xmin = (k == 0) ? 0 : occ[k - 1] + 1;
    const int s_end = (n - 1) / 6;      // number of full rank-6 steps (8..15)
    const int jend  = 6 * s_end;

    if (tid == 0) { step_pub = -1; gs_runprod = 1.0; gs_dead = 0; evmmask = 0; }
    if (tid < 16) { evmask16[tid] = 0; sdead16[tid] = 0; }
    if (tid < Dd) flag[tid] = 0;
    __syncthreads();
    if (tid < k) flag[occ[tid]] = 1;
    __syncthreads();                    // flags ready before diag-add

    double myprob = 0.0;
    double rr[6][2];                    // my 6 rows x my 2 cols
    const bool active = (wave <= s_end);

    if (active) {
        // ---- fused register build: rr = my 6 rows of -P P^T (+ diag) ----
        // Element-wise, t-ascending: bit-identical to the split build_g.
        double acc[6][2];
#pragma unroll
        for (int u = 0; u < 6; ++u) { acc[u][0] = 0.0; acc[u][1] = 0.0; }
        if (lane < 48) {
            const float* pc0 = P + (2 * lane) * 48;
            const float* pc1 = pc0 + 48;
            const float* pr0 = P + (6 * wave) * 48;
            for (int t4 = 0; t4 < 12; ++t4) {
                float4 v0 = ((const float4*)pc0)[t4];
                float4 v1 = ((const float4*)pc1)[t4];
#pragma unroll
                for (int u = 0; u < 6; ++u) {
                    float4 vr = ((const float4*)(pr0 + u * 48))[t4];
                    acc[u][0] -= (double)vr.x * (double)v0.x;
                    acc[u][0] -= (double)vr.y * (double)v0.y;
                    acc[u][0] -= (double)vr.z * (double)v0.z;
                    acc[u][0] -= (double)vr.w * (double)v0.w;
                    acc[u][1] -= (double)vr.x * (double)v1.x;
                    acc[u][1] -= (double)vr.y * (double)v1.y;
                    acc[u][1] -= (double)vr.z * (double)v1.z;
                    acc[u][1] -= (double)vr.w * (double)v1.w;
                }
            }
        }
#pragma unroll
        for (int u = 0; u < 6; ++u) {
            if (lane < 48) {
                const int row = 6 * wave + u;
                double d0 = (row == 2 * lane     && !flag[row]) ? 1.0 : 0.0;
                double d1 = (row == 2 * lane + 1 && !flag[row]) ? 1.0 : 0.0;
                rr[u][0] = acc[u][0] + d0;
                rr[u][1] = acc[u][1] + d1;
            } else { rr[u][0] = 0.0; rr[u][1] = 0.0; }
        }

        // Owner-wave shuffle-GJ (in place: rr -> S = B^-1 R), guard chain,
        // emission/gs writes, Sbuf[p] publish + release-store of step_pub.
        // Next-pivot row updated first in each column (bit-identical).
        auto prefactor = [&](int p) {
            const int jb = 6 * p, jbH = 3 * p;
            double grun = gs_runprod; int gdead = gs_dead;
            int msk = 0;
#pragma unroll
            for (int cc = 0; cc < 6; ++cc) {
                const int src = jbH + (cc >> 1);
                double piv = rdlane(rr[cc][cc & 1], src);
                if (!gdead) {
                    double ap = fabs(piv);
                    int jj = jb + cc;
                    if (jj >= xmin) {
                        if (lane == 0) ev16[p][cc] = grun * (1.0 - piv);  // emit BEFORE cut
                        msk |= (1 << cc);
                        double nr = grun * piv;
                        if (!(ap > 1e-7) || !(ap < 8.0) || !(fabs(nr) > 1e-8)) gdead = 1;
                        else grun = nr;
                    } else {
                        if (!(ap > 1e-12) || !(ap < 8.0)) gdead = 1;
                    }
                }
                double rp = frcp(piv);
                rr[cc][0] *= rp; rr[cc][1] *= rp;
                if (cc < 5) {           // next-pivot row first: shortens chain
                    double f = rdlane(rr[cc + 1][cc & 1], src);
                    rr[cc + 1][0] -= f * rr[cc][0];
                    rr[cc + 1][1] -= f * rr[cc][1];
                }
#pragma unroll
                for (int i = 0; i < 6; ++i) {
                    if (i == cc || i == cc + 1) continue;
                    double f = rdlane(rr[i][cc & 1], src);
                    rr[i][0] -= f * rr[cc][0];
                    rr[i][1] -= f * rr[cc][1];
                }
            }
            if (lane == 0) {
                evmask16[p] = msk; sdead16[p] = gdead;
                gs_runprod = grun; gs_dead = gdead;
            }
            if (lane < 48) {
                const bool live = (2 * lane >= jb + 6);
#pragma unroll
                for (int r = 0; r < 6; ++r) {
                    double2 sv;
                    sv.x = live ? rr[r][0] : 0.0;
                    sv.y = live ? rr[r][1] : 0.0;
                    *(double2*)&Sbuf[p][r][2 * lane] = sv;
                }
            }
            __threadfence_block();
            if (lane == 0)
                __hip_atomic_store(&step_pub, p, __ATOMIC_RELEASE, __HIP_MEMORY_SCOPE_WORKGROUP);
        };

        if (wave == 0) prefactor(0);    // seed: needs only wave 0's own rows

        // ---- async rank-6 pipeline ----
        bool broke = false;
        const int smax = (wave < s_end) ? wave : s_end;
        for (int s = 0; s < smax; ++s) {
            const bool nextOwner = (wave == s + 1);
            if (nextOwner) {            // tight spin: no wake quantum on chain
                while (__hip_atomic_load(&step_pub, __ATOMIC_ACQUIRE,
                                         __HIP_MEMORY_SCOPE_WORKGROUP) < s) {}
            } else {                    // parked spin: less issue pollution
                while (__hip_atomic_load(&step_pub, __ATOMIC_ACQUIRE,
                                         __HIP_MEMORY_SCOPE_WORKGROUP) < s)
                    __builtin_amdgcn_s_sleep(2);
            }
            if (sdead16[s]) { broke = true; break; }
            if (nextOwner) __builtin_amdgcn_s_setprio(1);
            double S0[6], S1[6];
            if (lane < 48) {
#pragma unroll
                for (int r = 0; r < 6; ++r) {
                    double2 sv = *(const double2*)&Sbuf[s][r][2 * lane];
                    S0[r] = sv.x; S1[r] = sv.y;
                }
                const int al = 3 * s;   // lanes holding frozen panel cols j..j+5
#pragma unroll
                for (int u = 0; u < 6; ++u) {
#pragma unroll
                    for (int r = 0; r < 6; ++r) {
                        double a = rdlane(rr[u][r & 1], al + (r >> 1));
                        rr[u][0] -= a * S0[r];
                        rr[u][1] -= a * S1[r];
                    }
                }
            }
            if (nextOwner && s + 1 < s_end)
                prefactor(s + 1);
            if (nextOwner) __builtin_amdgcn_s_setprio(0);
        }

        // ---- tail mini-LU (rows jend..n-1 live in wave s_end's registers) ----
        if (!broke && wave == s_end) {
            const int rsz = n - jend;            // 1..6
            double grun = gs_runprod; int gdead = gs_dead;
            int msk = 0;
#pragma unroll
            for (int cc = 0; cc < 6; ++cc) {
                const int src = 3 * s_end + (cc >> 1);
                double piv = rdlane(rr[cc][cc & 1], src);
                double evv = 0.0;
                if (cc < rsz - 1) {              // interior pivot
                    if (!gdead) {
                        double ap = fabs(piv);
                        int jj = jend + cc;
                        if (jj >= xmin) {
                            evv = grun * (1.0 - piv); msk |= (1 << cc);
                            double nr = grun * piv;
                            if (!(ap > 1e-7) || !(ap < 8.0) || !(fabs(nr) > 1e-8)) gdead = 1;
                            else grun = nr;
                        } else {
                            if (!(ap > 1e-12) || !(ap < 8.0)) gdead = 1;
                        }
                    }
                } else if (cc == rsz - 1) {      // x = xmax-1: remaining mass
                    if (!gdead) { evv = grun * (1.0 - piv); msk |= (1 << cc); }
                }
                if (lane == 0) evm[cc] = evv;
                double rp = frcp(piv);
                rr[cc][0] *= rp; rr[cc][1] *= rp;
                if (cc < 5) {
                    double f = rdlane(rr[cc + 1][cc & 1], src);
                    rr[cc + 1][0] -= f * rr[cc][0];
                    rr[cc + 1][1] -= f * rr[cc][1];
                }
#pragma unroll
                for (int i = 0; i < 6; ++i) {
                    if (i == cc || i == cc + 1) continue;
                    double f = rdlane(rr[i][cc & 1], src);
                    rr[i][0] -= f * rr[cc][0];
                    rr[i][1] -= f * rr[cc][1];
                }
            }
            if (lane == 0) evmmask = msk;
        }
    }
    __syncthreads();                    // ONE barrier: everything published

    // ---- collect emissions ----
    if (tid < jend) {
        int sp = tid / 6, q = tid - 6 * sp;
        if ((evmask16[sp] >> q) & 1) myprob = ev16[sp][q];
    } else if (tid < n) {
        int q = tid - jend;
        if ((evmmask >> q) & 1) myprob = evm[q];
    }

    if (tid < Dd) {
        double p = myprob;
        if (!isfinite(p)) p = 0.0;
        if (!(fabs(p) > 1e-15)) p = 0.0;   // reference's flush
        p = fmin(fmax(p, 0.0), 1.0);       // junk-proof projection
        out[k * Dd + tid] = (float)p;
    }

    // ---- merged prob_sample: last-arriving block does the product ----
    __threadfence();
    __syncthreads();
    if (wave == 0) {
        int old = 0;
        if (lane == 0)
            old = (int)__hip_atomic_fetch_add(cnt, 1u, __ATOMIC_ACQ_REL,
                                              __HIP_MEMORY_SCOPE_AGENT);
        old = __shfl(old, 0, 64);
        // Exactly one multiple of Nn in any Nn consecutive values -> exactly
        // one trigger per launch for ANY initial/poisoned counter value.
        if (((unsigned)old + 1u) % (unsigned)Nn == 0u) {
            __threadfence();            // acquire side
            double v = 1.0;
            if (lane < Nn) {
                float f = __hip_atomic_load(out + lane * Dd + occ[lane],
                                            __ATOMIC_RELAXED, __HIP_MEMORY_SCOPE_AGENT);
                v = (double)f;
            }
#pragma unroll
            for (int off = 32; off >= 1; off >>= 1)
                v *= __shfl_down(v, off, 64);
            if (lane == 0) {
                if (!isfinite(v)) v = 0.0;
                out[Nn * Dd] = (float)v;
            }
        }
    }
}

extern "C" void kernel_launch(void* const* d_in, const int* in_sizes, int n_in,
                              void* d_out, int out_size, void* d_ws, size_t ws_size,
                              hipStream_t stream) {
    const float* P = (const float*)d_in[0];      // 96x48 f32, row-major
    const int* occ = (const int*)d_in[1];        // 48 int32
    float* out = (float*)d_out;                  // 4609 f32

    slater_fused<<<Nn, 1024, 0, stream>>>(P, occ, out, (unsigned*)d_ws);
}

// Round 14
// 90.715 us; speedup vs baseline: 1.0859x; 1.0859x over previous
//
#include <hip/hip_runtime.h>
#include <math.h>

#define Dd 96
#define Nn 48
#define LD 97
#define PTS 98   // even stride (mono fallback only)
#define WS_G_BYTES (Dd * Dd * 8)   // 73,728 B for shared G matrix

// Fast full-precision f64 reciprocal: v_rcp_f64 + 2 Newton steps (<=1 ulp).
__device__ __forceinline__ double frcp(double x) {
    double r = __builtin_amdgcn_rcp(x);
    r = fma(fma(-x, r, 1.0), r, r);
    r = fma(fma(-x, r, 1.0), r, r);
    return r;
}

// Wave-uniform f64 broadcast from a lane (v_readlane -> SGPR pair, no LDS).
__device__ __forceinline__ double rdlane(double v, int srcLane) {
    union { double d; int i[2]; } u; u.d = v;
    int lo = __builtin_amdgcn_readlane(u.i[0], srcLane);
    int hi = __builtin_amdgcn_readlane(u.i[1], srcLane);
    union { int i[2]; double d; } w; w.i[0] = lo; w.i[1] = hi;
    return w.d;
}

// ============================================================================
// K1: G-matrix build, ONCE for all blocks. M[r][c] = -sum_t P[r][t]P[c][t].
// Runs as 36 blocks on separate CUs -> fully parallel, off the chain's
// critical path (R32 lesson: fusing this into the elim kernel put 576 serial
// f64 FMAs ahead of prefactor(0) and issue-polluted the pipeline: -7.4 µs).
// ============================================================================
__global__ __launch_bounds__(256) void build_g(const float* __restrict__ P,
                                               double* __restrict__ Mg) {
    __shared__ float Ps[Dd * 48];       // 18,432 B
    const int t0 = threadIdx.x;
    for (int e = t0; e < Dd * 48; e += 256) Ps[e] = P[e];
    __syncthreads();
    const int e = blockIdx.x * 256 + t0;     // 0..9215
    const int r = e / Dd, c = e - Dd * (e / Dd);
    const float* pr = Ps + r * 48;
    const float* pc = Ps + c * 48;
    double acc = 0.0;
#pragma unroll
    for (int t = 0; t < 48; ++t)
        acc -= (double)pr[t] * (double)pc[t];
    Mg[e] = acc;
}

// ============================================================================
// R31 K2 (measured best, 91.08 µs): rank-6 async pipeline with protocol cuts:
//  (1) Sbuf depth 16 (one buffer/step, 74KB LDS) -> no consumption counters.
//  (2) s_setprio(1) around next-owner's consume+prefactor.
//  (3) asymmetric spins: next-owner tight-polls; consumers s_sleep(2).
// ============================================================================
__global__ __launch_bounds__(1024, 1) void slater_elim(const double* __restrict__ Mg,
                                                       const int* __restrict__ occ,
                                                       float* __restrict__ out,
                                                       unsigned* __restrict__ cnt) {
    __shared__ double Sbuf[16][6][Dd];  // 73,728 B: one S buffer per step
    __shared__ double ev16[16][6];      // per-panel emissions
    __shared__ int    evmask16[16], sdead16[16];
    __shared__ double evm[6];           // mini-LU emissions
    __shared__ int    evmmask;
    __shared__ double gs_runprod;       // guard-state chain (owner-serialized)
    __shared__ int    gs_dead;
    __shared__ int    step_pub;         // highest published step (monotonic)
    __shared__ unsigned char flag[Dd];

    const int tid  = threadIdx.x;
    const int k    = blockIdx.x;
    const int n    = Dd - Nn + k + 1;   // xmax
    const int lane = tid & 63;
    const int wave = tid >> 6;          // 0..15
    const int xmin = (k == 0) ? 0 : occ[k - 1] + 1;
    const int s_end = (n - 1) / 6;      // number of full rank-6 steps (8..15)
    const int jend  = 6 * s_end;

    if (tid == 0) { step_pub = -1; gs_runprod = 1.0; gs_dead = 0; evmmask = 0; }
    if (tid < 16) { evmask16[tid] = 0; sdead16[tid] = 0; }
    if (tid < Dd) flag[tid] = 0;
    __syncthreads();
    if (tid < k) flag[occ[tid]] = 1;
    __syncthreads();                    // flags ready before rr load

    double myprob = 0.0;
    double rr[6][2];                    // my 6 rows x my 2 cols

    // ---- load my rows from the shared G (global, L2-broadcast) ----
#pragma unroll
    for (int u = 0; u < 6; ++u) {
        if (lane < 48) {
            const int row = 6 * wave + u;
            double2 g = *(const double2*)(Mg + row * Dd + 2 * lane);
            double d0 = (row == 2 * lane     && !flag[row]) ? 1.0 : 0.0;
            double d1 = (row == 2 * lane + 1 && !flag[row]) ? 1.0 : 0.0;
            rr[u][0] = g.x + d0;
            rr[u][1] = g.y + d1;
        } else { rr[u][0] = 0.0; rr[u][1] = 0.0; }
    }

    // Owner-wave shuffle-GJ (in place: rr -> S = B^-1 R), guard chain,
    // emission/gs writes, Sbuf[p] publish + release-store of step_pub.
    // Next-pivot row updated first in each column (bit-identical).
    auto prefactor = [&](int p) {
        const int jb = 6 * p, jbH = 3 * p;
        double grun = gs_runprod; int gdead = gs_dead;
        int msk = 0;
#pragma unroll
        for (int cc = 0; cc < 6; ++cc) {
            const int src = jbH + (cc >> 1);
            double piv = rdlane(rr[cc][cc & 1], src);
            if (!gdead) {
                double ap = fabs(piv);
                int jj = jb + cc;
                if (jj >= xmin) {
                    if (lane == 0) ev16[p][cc] = grun * (1.0 - piv);  // emit BEFORE cut
                    msk |= (1 << cc);
                    double nr = grun * piv;
                    if (!(ap > 1e-7) || !(ap < 8.0) || !(fabs(nr) > 1e-8)) gdead = 1;
                    else grun = nr;
                } else {
                    if (!(ap > 1e-12) || !(ap < 8.0)) gdead = 1;
                }
            }
            double rp = frcp(piv);
            rr[cc][0] *= rp; rr[cc][1] *= rp;
            if (cc < 5) {               // next-pivot row first: shortens chain
                double f = rdlane(rr[cc + 1][cc & 1], src);
                rr[cc + 1][0] -= f * rr[cc][0];
                rr[cc + 1][1] -= f * rr[cc][1];
            }
#pragma unroll
            for (int i = 0; i < 6; ++i) {
                if (i == cc || i == cc + 1) continue;
                double f = rdlane(rr[i][cc & 1], src);
                rr[i][0] -= f * rr[cc][0];
                rr[i][1] -= f * rr[cc][1];
            }
        }
        if (lane == 0) {
            evmask16[p] = msk; sdead16[p] = gdead;
            gs_runprod = grun; gs_dead = gdead;
        }
        if (lane < 48) {
            const bool live = (2 * lane >= jb + 6);
#pragma unroll
            for (int r = 0; r < 6; ++r) {
                double2 sv;
                sv.x = live ? rr[r][0] : 0.0;
                sv.y = live ? rr[r][1] : 0.0;
                *(double2*)&Sbuf[p][r][2 * lane] = sv;
            }
        }
        __threadfence_block();
        if (lane == 0)
            __hip_atomic_store(&step_pub, p, __ATOMIC_RELEASE, __HIP_MEMORY_SCOPE_WORKGROUP);
    };

    if (wave == 0) prefactor(0);        // seed the pipeline

    // ---- async rank-6 pipeline: wave w participates in steps 0..min(w,s_end)-1 ----
    bool broke = false;
    const int smax = (wave < s_end) ? wave : s_end;
    for (int s = 0; s < smax; ++s) {
        const bool nextOwner = (wave == s + 1);
        if (nextOwner) {                // tight spin: no wake quantum on chain
            while (__hip_atomic_load(&step_pub, __ATOMIC_ACQUIRE,
                                     __HIP_MEMORY_SCOPE_WORKGROUP) < s) {}
        } else {                        // parked spin: less issue pollution
            while (__hip_atomic_load(&step_pub, __ATOMIC_ACQUIRE,
                                     __HIP_MEMORY_SCOPE_WORKGROUP) < s)
                __builtin_amdgcn_s_sleep(2);
        }
        if (sdead16[s]) { broke = true; break; }
        if (nextOwner) __builtin_amdgcn_s_setprio(1);
        double S0[6], S1[6];
        if (lane < 48) {
#pragma unroll
            for (int r = 0; r < 6; ++r) {
                double2 sv = *(const double2*)&Sbuf[s][r][2 * lane];
                S0[r] = sv.x; S1[r] = sv.y;
            }
            const int al = 3 * s;       // lanes holding frozen panel cols j..j+5
#pragma unroll
            for (int u = 0; u < 6; ++u) {
#pragma unroll
                for (int r = 0; r < 6; ++r) {
                    double a = rdlane(rr[u][r & 1], al + (r >> 1));
                    rr[u][0] -= a * S0[r];
                    rr[u][1] -= a * S1[r];
                }
            }
        }
        if (nextOwner && s + 1 < s_end)
            prefactor(s + 1);
        if (nextOwner) __builtin_amdgcn_s_setprio(0);
    }

    // ---- tail mini-LU (rows jend..n-1 live in wave s_end's registers) ----
    if (!broke && wave == s_end) {
        const int rsz = n - jend;                // 1..6
        double grun = gs_runprod; int gdead = gs_dead;
        int msk = 0;
#pragma unroll
        for (int cc = 0; cc < 6; ++cc) {
            const int src = 3 * s_end + (cc >> 1);
            double piv = rdlane(rr[cc][cc & 1], src);
            double evv = 0.0;
            if (cc < rsz - 1) {                  // interior pivot
                if (!gdead) {
                    double ap = fabs(piv);
                    int jj = jend + cc;
                    if (jj >= xmin) {
                        evv = grun * (1.0 - piv); msk |= (1 << cc);
                        double nr = grun * piv;
                        if (!(ap > 1e-7) || !(ap < 8.0) || !(fabs(nr) > 1e-8)) gdead = 1;
                        else grun = nr;
                    } else {
                        if (!(ap > 1e-12) || !(ap < 8.0)) gdead = 1;
                    }
                }
            } else if (cc == rsz - 1) {          // x = xmax-1: remaining mass
                if (!gdead) { evv = grun * (1.0 - piv); msk |= (1 << cc); }
            }
            if (lane == 0) evm[cc] = evv;
            double rp = frcp(piv);
            rr[cc][0] *= rp; rr[cc][1] *= rp;
            if (cc < 5) {
                double f = rdlane(rr[cc + 1][cc & 1], src);
                rr[cc + 1][0] -= f * rr[cc][0];
                rr[cc + 1][1] -= f * rr[cc][1];
            }
#pragma unroll
            for (int i = 0; i < 6; ++i) {
                if (i == cc || i == cc + 1) continue;
                double f = rdlane(rr[i][cc & 1], src);
                rr[i][0] -= f * rr[cc][0];
                rr[i][1] -= f * rr[cc][1];
            }
        }
        if (lane == 0) evmmask = msk;
    }
    __syncthreads();                    // ONE barrier: everything published

    // ---- collect emissions ----
    if (tid < jend) {
        int sp = tid / 6, q = tid - 6 * sp;
        if ((evmask16[sp] >> q) & 1) myprob = ev16[sp][q];
    } else if (tid < n) {
        int q = tid - jend;
        if ((evmmask >> q) & 1) myprob = evm[q];
    }

    if (tid < Dd) {
        double p = myprob;
        if (!isfinite(p)) p = 0.0;
        if (!(fabs(p) > 1e-15)) p = 0.0;   // reference's flush
        p = fmin(fmax(p, 0.0), 1.0);       // junk-proof projection
        out[k * Dd + tid] = (float)p;
    }

    // ---- merged prob_sample: last-arriving block does the product ----
    __threadfence();
    __syncthreads();
    if (wave == 0) {
        int old = 0;
        if (lane == 0)
            old = (int)__hip_atomic_fetch_add(cnt, 1u, __ATOMIC_ACQ_REL,
                                              __HIP_MEMORY_SCOPE_AGENT);
        old = __shfl(old, 0, 64);
        if (((unsigned)old + 1u) % (unsigned)Nn == 0u) {
            __threadfence();            // acquire side
            double v = 1.0;
            if (lane < Nn) {
                float f = __hip_atomic_load(out + lane * Dd + occ[lane],
                                            __ATOMIC_RELAXED, __HIP_MEMORY_SCOPE_AGENT);
                v = (double)f;
            }
#pragma unroll
            for (int off = 32; off >= 1; off >>= 1)
                v *= __shfl_down(v, off, 64);
            if (lane == 0) {
                if (!isfinite(v)) v = 0.0;
                out[Nn * Dd] = (float)v;
            }
        }
    }
}

// ============================================================================
// Fallback: monolithic kernel (used only if ws is too small).
// ============================================================================
__global__ __launch_bounds__(1024, 1) void slater_mono(const float* __restrict__ P,
                                                       const int* __restrict__ occ,
                                                       float* __restrict__ out,
                                                       unsigned* __restrict__ cnt) {
    __shared__ double As[Dd * LD];
    __shared__ double Sbuf[4][6][Dd];
    __shared__ double ev16[16][6];
    __shared__ int    evmask16[16], sdead16[16];
    __shared__ double evm[6];
    __shared__ int    evmmask;
    __shared__ double gs_runprod;
    __shared__ int    gs_dead;
    __shared__ int    step_pub;
    __shared__ int    done4[4];
    __shared__ unsigned char flag[Dd];
    float* PT = (float*)As;

    const int tid  = threadIdx.x;
    const int k    = blockIdx.x;
    const int n    = Dd - Nn + k + 1;
    const int lane = tid & 63;
    const int wave = tid >> 6;
    const int xmin = (k == 0) ? 0 : occ[k - 1] + 1;
    const int s_end = (n - 1) / 6;
    const int jend  = 6 * s_end;

    if (tid == 0) { step_pub = -1; gs_runprod = 1.0; gs_dead = 0; evmmask = 0; }
    if (tid < 4)  done4[tid] = 0;
    if (tid < 16) { evmask16[tid] = 0; sdead16[tid] = 0; }
    if (tid < Dd) flag[tid] = 0;
    __syncthreads();
    if (tid < k) flag[occ[tid]] = 1;
    for (int e = tid; e < Dd * Nn; e += 1024) {
        int c = e / Nn, t = e - (e / Nn) * Nn;
        PT[t * PTS + c] = P[e];
    }
    __syncthreads();

    double Areg[8]; int trs[2], tcs[2];
#pragma unroll
    for (int it = 0; it < 2; ++it) {
        int tau = tid + 1024 * it;
        double s00 = 0.0, s01 = 0.0, s10 = 0.0, s11 = 0.0;
        int tr = 0, tc = 0;
        if (tau < 1176) {
            tr = (int)((97.0 - sqrt(9409.0 - 8.0 * (double)tau)) * 0.5);
            while ((tr * (97 - tr)) / 2 > tau) --tr;
            while (((tr + 1) * (96 - tr)) / 2 <= tau) ++tr;
            tc = tr + (tau - (tr * (97 - tr)) / 2);
            int r0 = 2 * tr, c0 = 2 * tc;
            if (r0 < n && c0 < n) {
                for (int t = 0; t < Nn; ++t) {
                    const float* row = PT + t * PTS;
                    float2 pr = *(const float2*)(row + r0);
                    float2 pc = *(const float2*)(row + c0);
                    s00 -= (double)pr.x * (double)pc.x; s01 -= (double)pr.x * (double)pc.y;
                    s10 -= (double)pr.y * (double)pc.x; s11 -= (double)pr.y * (double)pc.y;
                }
            }
        }
        trs[it] = tr; tcs[it] = tc;
        Areg[it * 4 + 0] = s00; Areg[it * 4 + 1] = s01;
        Areg[it * 4 + 2] = s10; Areg[it * 4 + 3] = s11;
    }
    __syncthreads();
#pragma unroll
    for (int it = 0; it < 2; ++it) {
        int tau = tid + 1024 * it;
        if (tau < 1176) {
            int tr = trs[it], tc = tcs[it];
            int r0 = 2 * tr, c0 = 2 * tc;
            if (r0 < n && c0 < n) {
                bool r1 = (r0 + 1 < n), c1 = (c0 + 1 < n);
                double d0 = flag[r0] ? 0.0 : 1.0;
                double d1 = flag[r0 + 1] ? 0.0 : 1.0;
                As[r0 * LD + c0] = Areg[it * 4 + 0] + ((r0 == c0) ? d0 : 0.0);
                if (c1)       As[r0 * LD + c0 + 1]       = Areg[it * 4 + 1];
                if (r1)       As[(r0 + 1) * LD + c0]     = Areg[it * 4 + 2];
                if (r1 && c1) As[(r0 + 1) * LD + c0 + 1] = Areg[it * 4 + 3] + ((r0 == c0) ? d1 : 0.0);
                if (tr != tc) {
                    As[c0 * LD + r0] = Areg[it * 4 + 0];
                    if (c1)       As[(c0 + 1) * LD + r0]     = Areg[it * 4 + 1];
                    if (r1)       As[c0 * LD + r0 + 1]       = Areg[it * 4 + 2];
                    if (r1 && c1) As[(c0 + 1) * LD + r0 + 1] = Areg[it * 4 + 3];
                }
            }
        }
    }
    __syncthreads();

    double myprob = 0.0;
    double rr[6][2];
#pragma unroll
    for (int u = 0; u < 6; ++u) {
        if (lane < 48) {
            rr[u][0] = As[(6 * wave + u) * LD + 2 * lane];
            rr[u][1] = As[(6 * wave + u) * LD + 2 * lane + 1];
        } else { rr[u][0] = 0.0; rr[u][1] = 0.0; }
    }

    auto prefactor = [&](int p, int slot) {
        const int jb = 6 * p, jbH = 3 * p;
        double grun = gs_runprod; int gdead = gs_dead;
        int msk = 0;
#pragma unroll
        for (int cc = 0; cc < 6; ++cc) {
            const int src = jbH + (cc >> 1);
            double piv = rdlane(rr[cc][cc & 1], src);
            if (!gdead) {
                double ap = fabs(piv);
                int jj = jb + cc;
                if (jj >= xmin) {
                    if (lane == 0) ev16[p][cc] = grun * (1.0 - piv);
                    msk |= (1 << cc);
                    double nr = grun * piv;
                    if (!(ap > 1e-7) || !(ap < 8.0) || !(fabs(nr) > 1e-8)) gdead = 1;
                    else grun = nr;
                } else {
                    if (!(ap > 1e-12) || !(ap < 8.0)) gdead = 1;
                }
            }
            double rp = frcp(piv);
            rr[cc][0] *= rp; rr[cc][1] *= rp;
#pragma unroll
            for (int i = 0; i < 6; ++i) {
                if (i == cc) continue;
                double f = rdlane(rr[i][cc & 1], src);
                rr[i][0] -= f * rr[cc][0];
                rr[i][1] -= f * rr[cc][1];
            }
        }
        if (lane == 0) {
            evmask16[p] = msk; sdead16[p] = gdead;
            gs_runprod = grun; gs_dead = gdead;
        }
        if (lane < 48) {
            const bool live = (2 * lane >= jb + 6);
#pragma unroll
            for (int r = 0; r < 6; ++r) {
                double2 sv;
                sv.x = live ? rr[r][0] : 0.0;
                sv.y = live ? rr[r][1] : 0.0;
                *(double2*)&Sbuf[slot][r][2 * lane] = sv;
            }
        }
        __threadfence_block();
        if (lane == 0)
            __hip_atomic_store(&step_pub, p, __ATOMIC_RELEASE, __HIP_MEMORY_SCOPE_WORKGROUP);
    };

    if (wave == 0) prefactor(0, 0);

    bool broke = false;
    const int smax = (wave < s_end) ? wave : s_end;
    for (int s = 0; s < smax; ++s) {
        while (__hip_atomic_load(&step_pub, __ATOMIC_ACQUIRE,
                                 __HIP_MEMORY_SCOPE_WORKGROUP) < s)
            __builtin_amdgcn_s_sleep(1);
        if (sdead16[s]) { broke = true; break; }
        const int slot = s & 3;
        double S0[6], S1[6];
        if (lane < 48) {
#pragma unroll
            for (int r = 0; r < 6; ++r) {
                double2 sv = *(const double2*)&Sbuf[slot][r][2 * lane];
                S0[r] = sv.x; S1[r] = sv.y;
            }
        }
        asm volatile("s_waitcnt lgkmcnt(0)" ::: "memory");
        if (lane == 0)
            __hip_atomic_fetch_add(&done4[slot], 1, __ATOMIC_RELAXED,
                                   __HIP_MEMORY_SCOPE_WORKGROUP);
        if (lane < 48) {
            const int al = 3 * s;
#pragma unroll
            for (int u = 0; u < 6; ++u) {
#pragma unroll
                for (int r = 0; r < 6; ++r) {
                    double a = rdlane(rr[u][r & 1], al + (r >> 1));
                    rr[u][0] -= a * S0[r];
                    rr[u][1] -= a * S1[r];
                }
            }
        }
        if (wave == s + 1 && s + 1 < s_end) {
            const int p = s + 1;
            if (p >= 4) {
                const int q = p & 3, m = p >> 2;
                const int T = m * (15 - q) - 2 * m * (m - 1);
                while (__hip_atomic_load(&done4[q], __ATOMIC_ACQUIRE,
                                         __HIP_MEMORY_SCOPE_WORKGROUP) < T)
                    __builtin_amdgcn_s_sleep(1);
            }
            prefactor(p, p & 3);
        }
    }

    if (!broke && wave == s_end) {
        const int rsz = n - jend;
        double grun = gs_runprod; int gdead = gs_dead;
        int msk = 0;
#pragma unroll
        for (int cc = 0; cc < 6; ++cc) {
            const int src = 3 * s_end + (cc >> 1);
            double piv = rdlane(rr[cc][cc & 1], src);
            double evv = 0.0;
            if (cc < rsz - 1) {
                if (!gdead) {
                    double ap = fabs(piv);
                    int jj = jend + cc;
                    if (jj >= xmin) {
                        evv = grun * (1.0 - piv); msk |= (1 << cc);
                        double nr = grun * piv;
                        if (!(ap > 1e-7) || !(ap < 8.0) || !(fabs(nr) > 1e-8)) gdead = 1;
                        else grun = nr;
                    } else {
                        if (!(ap > 1e-12) || !(ap < 8.0)) gdead = 1;
                    }
                }
            } else if (cc == rsz - 1) {
                if (!gdead) { evv = grun * (1.0 - piv); msk |= (1 << cc); }
            }
            if (lane == 0) evm[cc] = evv;
            double rp = frcp(piv);
            rr[cc][0] *= rp; rr[cc][1] *= rp;
#pragma unroll
            for (int i = 0; i < 6; ++i) {
                if (i == cc) continue;
                double f = rdlane(rr[i][cc & 1], src);
                rr[i][0] -= f * rr[cc][0];
                rr[i][1] -= f * rr[cc][1];
            }
        }
        if (lane == 0) evmmask = msk;
    }
    __syncthreads();

    if (tid < jend) {
        int sp = tid / 6, q = tid - 6 * sp;
        if ((evmask16[sp] >> q) & 1) myprob = ev16[sp][q];
    } else if (tid < n) {
        int q = tid - jend;
        if ((evmmask >> q) & 1) myprob = evm[q];
    }

    if (tid < Dd) {
        double p = myprob;
        if (!isfinite(p)) p = 0.0;
        if (!(fabs(p) > 1e-15)) p = 0.0;
        p = fmin(fmax(p, 0.0), 1.0);
        out[k * Dd + tid] = (float)p;
    }

    __threadfence();
    __syncthreads();
    if (wave == 0) {
        int old = 0;
        if (lane == 0)
            old = (int)__hip_atomic_fetch_add(cnt, 1u, __ATOMIC_ACQ_REL,
                                              __HIP_MEMORY_SCOPE_AGENT);
        old = __shfl(old, 0, 64);
        if (((unsigned)old + 1u) % (unsigned)Nn == 0u) {
            __threadfence();
            double v = 1.0;
            if (lane < Nn) {
                float f = __hip_atomic_load(out + lane * Dd + occ[lane],
                                            __ATOMIC_RELAXED, __HIP_MEMORY_SCOPE_AGENT);
                v = (double)f;
            }
#pragma unroll
            for (int off = 32; off >= 1; off >>= 1)
                v *= __shfl_down(v, off, 64);
            if (lane == 0) {
                if (!isfinite(v)) v = 0.0;
                out[Nn * Dd] = (float)v;
            }
        }
    }
}

extern "C" void kernel_launch(void* const* d_in, const int* in_sizes, int n_in,
                              void* d_out, int out_size, void* d_ws, size_t ws_size,
                              hipStream_t stream) {
    const float* P = (const float*)d_in[0];      // 96x48 f32, row-major
    const int* occ = (const int*)d_in[1];        // 48 int32
    float* out = (float*)d_out;                  // 4609 f32

    if (ws_size >= (size_t)(WS_G_BYTES + 16)) {
        double* Mg = (double*)d_ws;
        unsigned* cnt = (unsigned*)((char*)d_ws + WS_G_BYTES);
        build_g<<<36, 256, 0, stream>>>(P, Mg);
        slater_elim<<<Nn, 1024, 0, stream>>>(Mg, occ, out, cnt);
    } else {
        slater_mono<<<Nn, 1024, 0, stream>>>(P, occ, out, (unsigned*)d_ws);
    }
}